// Round 1
// baseline (4399.125 us; speedup 1.0000x reference)
//
#include <hip/hip_runtime.h>

// Problem constants
#define Bq   8
#define Nn   512
#define Tt   24
#define NIDc 64
#define HIDc 256
#define HORc 24
#define Dd   12376      // Tt + Nn*Tt + NIDc
#define Mm   4096       // Bq*Nn

// GEMM tiling
#define BM 64
#define BN 64
#define BK 32

// ---------------------------------------------------------------------------
// Kernel 1: build level + x0 (written into the backcast region of d_out)
// x = concat[ hist/level , relu((adj*hist - level)/level) , node_emb[id] ]
// ---------------------------------------------------------------------------
__global__ __launch_bounds__(256) void build_x_kernel(
    const float* __restrict__ hist, const int* __restrict__ nid,
    const float* __restrict__ adj, const float* __restrict__ emb,
    float* __restrict__ x, float* __restrict__ level)
{
    int bn = blockIdx.x;          // 0..4095
    int b  = bn >> 9;             // /512
    __shared__ float sh[Tt];
    __shared__ float slv;
    int tid = threadIdx.x;
    const float* hrow = hist + (size_t)bn * Tt;
    if (tid < Tt) sh[tid] = hrow[tid];
    __syncthreads();
    if (tid == 0) {
        float m = sh[0];
        #pragma unroll
        for (int t = 1; t < Tt; t++) m = fmaxf(m, sh[t]);
        slv = m;
        level[bn] = m;
    }
    __syncthreads();
    float lv  = slv;
    float inv = (lv == 0.0f) ? 0.0f : 1.0f / lv;   // div_no_nan
    float* xr = x + (size_t)bn * Dd;
    if (tid < Tt) xr[tid] = sh[tid] * inv;
    const float* hb   = hist + (size_t)b * Nn * Tt;
    const float* arow = adj  + (size_t)bn * Nn;
    for (int idx = tid; idx < Nn * Tt; idx += 256) {
        int m_ = idx / Tt;
        int t  = idx - m_ * Tt;
        float v = arow[m_] * hb[m_ * Tt + t];
        float r = (v - lv) * inv;                  // div_no_nan: inv==0 -> 0
        xr[Tt + idx] = (r > 0.0f) ? r : 0.0f;      // where(>0, x, 0)
    }
    if (tid < NIDc) {
        int id = nid[bn];
        xr[Tt + Nn * Tt + tid] = emb[(size_t)id * NIDc + tid];
    }
}

// ---------------------------------------------------------------------------
// Generic fp32 SGEMM: C[M x N] = epi(A[M x K] @ B[K x N] + bias)
// EPI 0: C = relu(acc + bias)                  (h layers; requires N%BN==0)
// EPI 1: C = relu(X - (acc + bias))            (backcast; X may alias C)
// Block: 256 thr (16x16), thread tile 4x4, tile 64x64, BK=32.
// ---------------------------------------------------------------------------
template <int EPI>
__global__ __launch_bounds__(256) void gemm_kernel(
    const float* __restrict__ A, int lda,
    const float* __restrict__ B, int ldb,
    const float* __restrict__ bias,
    const float* __restrict__ X, int ldx,
    float* __restrict__ C, int ldc,
    int K, int N)
{
    __shared__ float As[BK][BM + 4];   // transposed, +4 pad keeps 16B align
    __shared__ float Bs[BK][BN];
    int tid  = threadIdx.x;
    int row0 = blockIdx.x * BM;
    int col0 = blockIdx.y * BN;
    int tr = tid >> 4;
    int tc = tid & 15;
    float acc[4][4];
    #pragma unroll
    for (int i = 0; i < 4; i++)
        #pragma unroll
        for (int j = 0; j < 4; j++) acc[i][j] = 0.0f;

    for (int k0 = 0; k0 < K; k0 += BK) {
        // stage A tile (BM x BK) transposed into As[k][m]
        #pragma unroll
        for (int f = tid; f < BM * BK / 4; f += 256) {
            int r  = f >> 3;            // / 8 float4s per row
            int kq = (f & 7) * 4;
            int gk = k0 + kq;
            float4 v;
            const float* ap = A + (size_t)(row0 + r) * lda;
            if (gk + 3 < K) {
                v = *(const float4*)(ap + gk);
            } else {
                v.x = (gk + 0 < K) ? ap[gk + 0] : 0.0f;
                v.y = (gk + 1 < K) ? ap[gk + 1] : 0.0f;
                v.z = (gk + 2 < K) ? ap[gk + 2] : 0.0f;
                v.w = (gk + 3 < K) ? ap[gk + 3] : 0.0f;
            }
            As[kq + 0][r] = v.x; As[kq + 1][r] = v.y;
            As[kq + 2][r] = v.z; As[kq + 3][r] = v.w;
        }
        // stage B tile (BK x BN)
        #pragma unroll
        for (int f = tid; f < BK * BN / 4; f += 256) {
            int kk = f >> 4;            // / 16 float4s per row
            int nq = (f & 15) * 4;
            int gk = k0 + kk;
            int gn = col0 + nq;
            float4 v = make_float4(0.f, 0.f, 0.f, 0.f);
            if (gk < K) {
                const float* bp = B + (size_t)gk * ldb;
                if (gn + 3 < N) {
                    v = *(const float4*)(bp + gn);
                } else {
                    v.x = (gn + 0 < N) ? bp[gn + 0] : 0.0f;
                    v.y = (gn + 1 < N) ? bp[gn + 1] : 0.0f;
                    v.z = (gn + 2 < N) ? bp[gn + 2] : 0.0f;
                    v.w = (gn + 3 < N) ? bp[gn + 3] : 0.0f;
                }
            }
            *(float4*)&Bs[kk][nq] = v;
        }
        __syncthreads();
        #pragma unroll
        for (int k = 0; k < BK; k++) {
            float4 a = *(const float4*)&As[k][tr * 4];
            float4 b = *(const float4*)&Bs[k][tc * 4];
            float av[4] = {a.x, a.y, a.z, a.w};
            float bv[4] = {b.x, b.y, b.z, b.w};
            #pragma unroll
            for (int i = 0; i < 4; i++)
                #pragma unroll
                for (int j = 0; j < 4; j++)
                    acc[i][j] = fmaf(av[i], bv[j], acc[i][j]);
        }
        __syncthreads();
    }

    // epilogue
    #pragma unroll
    for (int i = 0; i < 4; i++) {
        int r  = row0 + tr * 4 + i;
        int c0 = col0 + tc * 4;
        if (EPI == 0) {
            // N is a multiple of BN for this epilogue (N=256)
            float4 o;
            float v0 = acc[i][0] + bias[c0 + 0];
            float v1 = acc[i][1] + bias[c0 + 1];
            float v2 = acc[i][2] + bias[c0 + 2];
            float v3 = acc[i][3] + bias[c0 + 3];
            o.x = v0 > 0.f ? v0 : 0.f;
            o.y = v1 > 0.f ? v1 : 0.f;
            o.z = v2 > 0.f ? v2 : 0.f;
            o.w = v3 > 0.f ? v3 : 0.f;
            *(float4*)(C + (size_t)r * ldc + c0) = o;
        } else {
            if (c0 + 3 < N) {
                float4 xv = *(const float4*)(X + (size_t)r * ldx + c0);
                float v0 = xv.x - (acc[i][0] + bias[c0 + 0]);
                float v1 = xv.y - (acc[i][1] + bias[c0 + 1]);
                float v2 = xv.z - (acc[i][2] + bias[c0 + 2]);
                float v3 = xv.w - (acc[i][3] + bias[c0 + 3]);
                float4 o;
                o.x = v0 > 0.f ? v0 : 0.f;
                o.y = v1 > 0.f ? v1 : 0.f;
                o.z = v2 > 0.f ? v2 : 0.f;
                o.w = v3 > 0.f ? v3 : 0.f;
                *(float4*)(C + (size_t)r * ldc + c0) = o;
            } else {
                #pragma unroll
                for (int j = 0; j < 4; j++) {
                    int c = c0 + j;
                    if (c < N) {
                        float xv = X[(size_t)r * ldx + c];
                        float v  = xv - (acc[i][j] + bias[c]);
                        C[(size_t)r * ldc + c] = v > 0.f ? v : 0.f;
                    }
                }
            }
        }
    }
}

// ---------------------------------------------------------------------------
// Forecast GEMM: fc[4096 x 24] (+)= h[4096 x 256] @ Wf[256 x 24] + bf
// ---------------------------------------------------------------------------
__global__ __launch_bounds__(256) void gemm_forecast_kernel(
    const float* __restrict__ h, const float* __restrict__ Wf,
    const float* __restrict__ bf, float* __restrict__ fc, int accumulate)
{
    int gid = blockIdx.x * 256 + threadIdx.x;
    if (gid >= Mm * HORc) return;
    int row = gid / HORc;
    int col = gid - row * HORc;
    const float* hr = h + (size_t)row * HIDc;
    float acc = 0.0f;
    #pragma unroll 4
    for (int k = 0; k < HIDc; k++)
        acc = fmaf(hr[k], Wf[k * HORc + col], acc);
    acc += bf[col];
    if (accumulate) fc[gid] += acc;
    else            fc[gid]  = acc;
}

// ---------------------------------------------------------------------------
// finalize: forecast_out = fc * level
// ---------------------------------------------------------------------------
__global__ __launch_bounds__(256) void finalize_kernel(
    const float* __restrict__ fc, const float* __restrict__ level,
    float* __restrict__ out)
{
    int gid = blockIdx.x * 256 + threadIdx.x;
    if (gid >= Mm * HORc) return;
    out[gid] = fc[gid] * level[gid / HORc];
}

// ---------------------------------------------------------------------------
extern "C" void kernel_launch(void* const* d_in, const int* in_sizes, int n_in,
                              void* d_out, int out_size, void* d_ws, size_t ws_size,
                              hipStream_t stream)
{
    const float* hist  = (const float*)d_in[0];
    const int*   nid   = (const int*)  d_in[1];
    // d_in[2] time_of_day_in: unused by the reference
    const float* adj   = (const float*)d_in[3];
    const float* emb   = (const float*)d_in[4];
    const float* W_in  = (const float*)d_in[5];
    const float* b_in  = (const float*)d_in[6];
    const float* W_hid = (const float*)d_in[7];
    const float* b_hid = (const float*)d_in[8];
    const float* W_f   = (const float*)d_in[9];
    const float* b_f   = (const float*)d_in[10];
    const float* W_b   = (const float*)d_in[11];
    const float* b_b   = (const float*)d_in[12];

    float* out      = (float*)d_out;
    float* backcast = out;                        // (B,N,D) flat
    float* fout     = out + (size_t)Mm * Dd;      // (B,N,HOR) flat

    // workspace layout (~8.8 MB)
    char*  ws    = (char*)d_ws;
    float* level = (float*)(ws);                          // 4096 floats
    float* h0    = (float*)(ws + 16384);                  // 4096*256
    float* h1    = (float*)(ws + 16384 + 4194304);        // 4096*256
    float* fc    = (float*)(ws + 16384 + 2 * 4194304);    // 4096*24

    float* x = backcast;   // x buffer lives in d_out; backcast updates in place

    build_x_kernel<<<Mm, 256, 0, stream>>>(hist, nid, adj, emb, x, level);

    for (int i = 0; i < 3; i++) {
        const float* Wi  = W_in  + (size_t)i * Dd * HIDc;
        const float* bi  = b_in  + (size_t)i * HIDc;
        const float* Wh0 = W_hid + (size_t)(i * 2 + 0) * HIDc * HIDc;
        const float* bh0 = b_hid + (size_t)(i * 2 + 0) * HIDc;
        const float* Wh1 = W_hid + (size_t)(i * 2 + 1) * HIDc * HIDc;
        const float* bh1 = b_hid + (size_t)(i * 2 + 1) * HIDc;
        const float* Wfi = W_f   + (size_t)i * HIDc * HORc;
        const float* bfi = b_f   + (size_t)i * HORc;
        const float* Wbi = W_b   + (size_t)i * HIDc * Dd;
        const float* bbi = b_b   + (size_t)i * Dd;

        // h0 = relu(x @ W_in + b_in)        M=4096 K=12376 N=256
        gemm_kernel<0><<<dim3(Mm / BM, HIDc / BN), 256, 0, stream>>>(
            x, Dd, Wi, HIDc, bi, nullptr, 0, h0, HIDc, Dd, HIDc);
        // h1 = relu(h0 @ Wh0 + bh0)         K=256 N=256
        gemm_kernel<0><<<dim3(Mm / BM, HIDc / BN), 256, 0, stream>>>(
            h0, HIDc, Wh0, HIDc, bh0, nullptr, 0, h1, HIDc, HIDc, HIDc);
        // h0 = relu(h1 @ Wh1 + bh1)
        gemm_kernel<0><<<dim3(Mm / BM, HIDc / BN), 256, 0, stream>>>(
            h1, HIDc, Wh1, HIDc, bh1, nullptr, 0, h0, HIDc, HIDc, HIDc);
        // fc (+)= h0 @ W_f + b_f
        gemm_forecast_kernel<<<(Mm * HORc + 255) / 256, 256, 0, stream>>>(
            h0, Wfi, bfi, fc, i > 0 ? 1 : 0);
        // x = relu(x - (h0 @ W_b + b_b))    in place; K=256 N=12376
        gemm_kernel<1><<<dim3(Mm / BM, (Dd + BN - 1) / BN), 256, 0, stream>>>(
            h0, HIDc, Wbi, Dd, bbi, x, Dd, x, Dd, HIDc, Dd);
    }

    finalize_kernel<<<(Mm * HORc + 255) / 256, 256, 0, stream>>>(fc, level, fout);
}

// Round 2
// 1394.332 us; speedup vs baseline: 3.1550x; 3.1550x over previous
//
#include <hip/hip_runtime.h>

// Problem constants
#define Bq   8
#define Nn   512
#define Tt   24
#define NIDc 64
#define HIDc 256
#define HORc 24
#define Dd   12376      // Tt + Nn*Tt + NIDc
#define Mm   4096       // Bq*Nn
#define DdPad 12384     // Dd padded to multiple of 32 (K-pad for W_in^T)
#define NbPad 12416     // Dd padded to multiple of 128 (N-pad for W_b^T rows)
#define SPLITK 8
#define KCHUNK 1568     // ceil(12376/(8*32))*32

typedef float  f32x4  __attribute__((ext_vector_type(4)));
typedef short  bf16x8 __attribute__((ext_vector_type(8)));

__device__ __forceinline__ ushort f2bf(float f) {
    unsigned u = __float_as_uint(f);
    u += 0x7FFF + ((u >> 16) & 1);          // RNE; inputs finite
    return (ushort)(u >> 16);
}
__device__ __forceinline__ float bf2f(ushort h) {
    return __uint_as_float(((unsigned)h) << 16);
}

// ---------------------------------------------------------------------------
// build level + x0 (fp32, written into backcast region of d_out)
// ---------------------------------------------------------------------------
__global__ __launch_bounds__(256) void build_x_kernel(
    const float* __restrict__ hist, const int* __restrict__ nid,
    const float* __restrict__ adj, const float* __restrict__ emb,
    float* __restrict__ x, float* __restrict__ level)
{
    int bn = blockIdx.x;
    int b  = bn >> 9;
    __shared__ float sh[Tt];
    __shared__ float slv;
    int tid = threadIdx.x;
    const float* hrow = hist + (size_t)bn * Tt;
    if (tid < Tt) sh[tid] = hrow[tid];
    __syncthreads();
    if (tid == 0) {
        float m = sh[0];
        #pragma unroll
        for (int t = 1; t < Tt; t++) m = fmaxf(m, sh[t]);
        slv = m;
        level[bn] = m;
    }
    __syncthreads();
    float lv  = slv;
    float inv = (lv == 0.0f) ? 0.0f : 1.0f / lv;
    float* xr = x + (size_t)bn * Dd;
    if (tid < Tt) xr[tid] = sh[tid] * inv;
    const float* hb   = hist + (size_t)b * Nn * Tt;
    const float* arow = adj  + (size_t)bn * Nn;
    for (int idx = tid; idx < Nn * Tt; idx += 256) {
        int m_ = idx / Tt;
        int t  = idx - m_ * Tt;
        float v = arow[m_] * hb[m_ * Tt + t];
        float r = (v - lv) * inv;
        xr[Tt + idx] = (r > 0.0f) ? r : 0.0f;
    }
    if (tid < NIDc) {
        int id = nid[bn];
        xr[Tt + Nn * Tt + tid] = emb[(size_t)id * NIDc + tid];
    }
}

// ---------------------------------------------------------------------------
// W[K][N] fp32  ->  Bt[n][k] bf16 with K zero-padded to Kpad.
// grid.y covers Npad/64 so pad rows are zero-filled too.
// ---------------------------------------------------------------------------
__global__ __launch_bounds__(256) void transpose_w(
    const float* __restrict__ W, ushort* __restrict__ Bt,
    int K, int N, int Kpad)
{
    __shared__ ushort tile[32][72];
    const int k0 = blockIdx.x * 32;
    const int n0 = blockIdx.y * 64;
    const int tid = threadIdx.x;
    #pragma unroll
    for (int i = 0; i < 8; i++) {
        const int idx = tid + i * 256;
        const int kk = idx >> 6;
        const int nn = idx & 63;
        const int gk = k0 + kk, gn = n0 + nn;
        const float v = (gk < K && gn < N) ? W[(size_t)gk * N + gn] : 0.0f;
        tile[kk][nn] = f2bf(v);
    }
    __syncthreads();
    const int n  = tid >> 2;
    const int kc = (tid & 3) << 3;
    uint4 o;
    o.x = (unsigned)tile[kc + 0][n] | ((unsigned)tile[kc + 1][n] << 16);
    o.y = (unsigned)tile[kc + 2][n] | ((unsigned)tile[kc + 3][n] << 16);
    o.z = (unsigned)tile[kc + 4][n] | ((unsigned)tile[kc + 5][n] << 16);
    o.w = (unsigned)tile[kc + 6][n] | ((unsigned)tile[kc + 7][n] << 16);
    *(uint4*)(Bt + (size_t)(n0 + n) * Kpad + k0 + kc) = o;
}

// ---------------------------------------------------------------------------
// bf16 MFMA GEMM, 128x128 tile, 4 waves x (4x4) mfma_f32_16x16x32_bf16.
// A: row-major [M][lda], fp32 (AMODE 0, converted while staging) or bf16
// (AMODE 1). Bt: bf16 [n][k], ldbt = Kpad (no guards needed: pre-padded).
// EPI 0: raw fp32 partial (split-K, blockIdx.z selects slice)
// EPI 1: bf16 h = relu(acc + bias)
// EPI 2: fp32 C = relu(X - (acc + bias))   (X may alias C; col-guarded)
// ---------------------------------------------------------------------------
template <int AMODE, int EPI>
__global__ __launch_bounds__(256) void gemm_mfma(
    const void* __restrict__ Ap, int lda,
    const ushort* __restrict__ Bt, int ldbt,
    const float* __restrict__ bias,
    const float* __restrict__ X, int ldx,
    void* __restrict__ Cp, int ldc,
    int K, int N, int chunk)
{
    __shared__ ushort As[128][40];   // [m][k], stride 80B: 2-way bank alias (free)
    __shared__ ushort Bs[128][40];   // [n][k]
    const int tid  = threadIdx.x;
    const int row0 = blockIdx.x * 128;
    const int col0 = blockIdx.y * 128;
    const int spl  = blockIdx.z;
    const int kstart = spl * chunk;
    const int kend   = min(K, kstart + chunk);
    const int iters  = (kend - kstart + 31) >> 5;

    const int lane = tid & 63;
    const int wave = tid >> 6;
    const int quad = lane >> 4;
    const int l15  = lane & 15;
    const int wm   = (wave >> 1) * 64;   // wave row offset in tile
    const int wn   = (wave & 1) * 64;    // wave col offset in tile

    f32x4 acc[4][4];
    #pragma unroll
    for (int i = 0; i < 4; i++)
        #pragma unroll
        for (int j = 0; j < 4; j++)
            acc[i][j] = (f32x4){0.f, 0.f, 0.f, 0.f};

    for (int kt = 0; kt < iters; ++kt) {
        const int kb = kstart + (kt << 5);
        if (AMODE == 0) {
            const float* A = (const float*)Ap;
            #pragma unroll
            for (int f = tid; f < 1024; f += 256) {
                const int r  = f >> 3;
                const int kq = (f & 7) << 2;
                const int gk = kb + kq;
                const float* ap = A + (size_t)(row0 + r) * lda + gk;
                float4 v;
                if (gk + 4 <= kend) {
                    v = *(const float4*)ap;
                } else {
                    v.x = (gk + 0 < kend) ? ap[0] : 0.f;
                    v.y = (gk + 1 < kend) ? ap[1] : 0.f;
                    v.z = (gk + 2 < kend) ? ap[2] : 0.f;
                    v.w = (gk + 3 < kend) ? ap[3] : 0.f;
                }
                ushort4 o;
                o.x = f2bf(v.x); o.y = f2bf(v.y);
                o.z = f2bf(v.z); o.w = f2bf(v.w);
                *(ushort4*)&As[r][kq] = o;
            }
        } else {
            const ushort* A = (const ushort*)Ap;
            #pragma unroll
            for (int f = tid; f < 512; f += 256) {
                const int r  = f >> 2;
                const int ko = (f & 3) << 3;
                *(uint4*)&As[r][ko] =
                    *(const uint4*)(A + (size_t)(row0 + r) * lda + kb + ko);
            }
        }
        #pragma unroll
        for (int f = tid; f < 512; f += 256) {
            const int r  = f >> 2;
            const int ko = (f & 3) << 3;
            *(uint4*)&Bs[r][ko] =
                *(const uint4*)(Bt + (size_t)(col0 + r) * ldbt + kb + ko);
        }
        __syncthreads();
        bf16x8 af[4], bfr[4];
        #pragma unroll
        for (int i = 0; i < 4; i++)
            af[i] = *(const bf16x8*)&As[wm + i * 16 + l15][quad * 8];
        #pragma unroll
        for (int j = 0; j < 4; j++)
            bfr[j] = *(const bf16x8*)&Bs[wn + j * 16 + l15][quad * 8];
        #pragma unroll
        for (int i = 0; i < 4; i++)
            #pragma unroll
            for (int j = 0; j < 4; j++)
                acc[i][j] = __builtin_amdgcn_mfma_f32_16x16x32_bf16(
                    af[i], bfr[j], acc[i][j], 0, 0, 0);
        __syncthreads();
    }

    // Epilogue. C/D layout: col = lane&15, row = quad*4 + reg.
    #pragma unroll
    for (int i = 0; i < 4; i++) {
        #pragma unroll
        for (int j = 0; j < 4; j++) {
            const int rbase = row0 + wm + i * 16 + quad * 4;
            const int c     = col0 + wn + j * 16 + l15;
            #pragma unroll
            for (int r2 = 0; r2 < 4; r2++) {
                const float v = acc[i][j][r2];
                const int row = rbase + r2;
                if (EPI == 0) {
                    ((float*)Cp)[(size_t)spl * Mm * HIDc +
                                 (size_t)row * ldc + c] = v;
                } else if (EPI == 1) {
                    float o = v + bias[c];
                    o = o > 0.f ? o : 0.f;
                    ((ushort*)Cp)[(size_t)row * ldc + c] = f2bf(o);
                } else {
                    if (c < N) {
                        float o = X[(size_t)row * ldx + c] - (v + bias[c]);
                        o = o > 0.f ? o : 0.f;
                        ((float*)Cp)[(size_t)row * ldc + c] = o;
                    }
                }
            }
        }
    }
}

// ---------------------------------------------------------------------------
// h = relu(sum_s partial[s] + bias) -> bf16
// ---------------------------------------------------------------------------
__global__ __launch_bounds__(256) void reduce_hin(
    const float* __restrict__ partial, const float* __restrict__ bias,
    ushort* __restrict__ h)
{
    const int idx = blockIdx.x * 256 + threadIdx.x;   // < Mm*HIDc
    float s = bias[idx & (HIDc - 1)];
    #pragma unroll
    for (int j = 0; j < SPLITK; j++)
        s += partial[(size_t)j * (Mm * HIDc) + idx];
    s = s > 0.f ? s : 0.f;
    h[idx] = f2bf(s);
}

// ---------------------------------------------------------------------------
// fc[4096x24] (+)= h @ Wf + bf   (h bf16, Wf fp32)
// ---------------------------------------------------------------------------
__global__ __launch_bounds__(256) void gemm_forecast_kernel(
    const ushort* __restrict__ h, const float* __restrict__ Wf,
    const float* __restrict__ bf, float* __restrict__ fc, int accumulate)
{
    int gid = blockIdx.x * 256 + threadIdx.x;
    if (gid >= Mm * HORc) return;
    int row = gid / HORc;
    int col = gid - row * HORc;
    const ushort* hr = h + (size_t)row * HIDc;
    float acc = 0.0f;
    #pragma unroll 4
    for (int k = 0; k < HIDc; k++)
        acc = fmaf(bf2f(hr[k]), Wf[k * HORc + col], acc);
    acc += bf[col];
    if (accumulate) fc[gid] += acc;
    else            fc[gid]  = acc;
}

__global__ __launch_bounds__(256) void finalize_kernel(
    const float* __restrict__ fc, const float* __restrict__ level,
    float* __restrict__ out)
{
    int gid = blockIdx.x * 256 + threadIdx.x;
    if (gid >= Mm * HORc) return;
    out[gid] = fc[gid] * level[gid / HORc];
}

// ---------------------------------------------------------------------------
extern "C" void kernel_launch(void* const* d_in, const int* in_sizes, int n_in,
                              void* d_out, int out_size, void* d_ws, size_t ws_size,
                              hipStream_t stream)
{
    const float* hist  = (const float*)d_in[0];
    const int*   nid   = (const int*)  d_in[1];
    const float* adj   = (const float*)d_in[3];
    const float* emb   = (const float*)d_in[4];
    const float* W_in  = (const float*)d_in[5];
    const float* b_in  = (const float*)d_in[6];
    const float* W_hid = (const float*)d_in[7];
    const float* b_hid = (const float*)d_in[8];
    const float* W_f   = (const float*)d_in[9];
    const float* b_f   = (const float*)d_in[10];
    const float* W_b   = (const float*)d_in[11];
    const float* b_b   = (const float*)d_in[12];

    float* x    = (float*)d_out;                       // backcast region
    float* fout = (float*)d_out + (size_t)Mm * Dd;     // forecast region

    // ws layout (~74 MB)
    char* ws = (char*)d_ws;
    size_t off = 0;
    float*  level = (float*) (ws + off); off += 16384;
    float*  fc    = (float*) (ws + off); off += (size_t)Mm * HORc * 4;
    ushort* hA    = (ushort*)(ws + off); off += (size_t)Mm * HIDc * 2;
    ushort* hB    = (ushort*)(ws + off); off += (size_t)Mm * HIDc * 2;
    ushort* WtIn  = (ushort*)(ws + off); off += (size_t)3 * HIDc * DdPad * 2;
    ushort* WtHid = (ushort*)(ws + off); off += (size_t)6 * HIDc * HIDc * 2;
    ushort* WtB   = (ushort*)(ws + off); off += (size_t)3 * NbPad * HIDc * 2;
    float*  part  = (float*) (ws + off); off += (size_t)SPLITK * Mm * HIDc * 4;

    build_x_kernel<<<Mm, 256, 0, stream>>>(hist, nid, adj, emb, x, level);

    // weight transposes + bf16 conversion (every launch; graph-safe)
    for (int i = 0; i < 3; i++)
        transpose_w<<<dim3(DdPad / 32, HIDc / 64), 256, 0, stream>>>(
            W_in + (size_t)i * Dd * HIDc, WtIn + (size_t)i * HIDc * DdPad,
            Dd, HIDc, DdPad);
    for (int l = 0; l < 6; l++)
        transpose_w<<<dim3(HIDc / 32, HIDc / 64), 256, 0, stream>>>(
            W_hid + (size_t)l * HIDc * HIDc, WtHid + (size_t)l * HIDc * HIDc,
            HIDc, HIDc, HIDc);
    for (int i = 0; i < 3; i++)
        transpose_w<<<dim3(HIDc / 32, NbPad / 64), 256, 0, stream>>>(
            W_b + (size_t)i * HIDc * Dd, WtB + (size_t)i * NbPad * HIDc,
            HIDc, Dd, HIDc);

    for (int i = 0; i < 3; i++) {
        const float* bi  = b_in  + (size_t)i * HIDc;
        const float* bh0 = b_hid + (size_t)(i * 2 + 0) * HIDc;
        const float* bh1 = b_hid + (size_t)(i * 2 + 1) * HIDc;
        const float* Wfi = W_f   + (size_t)i * HIDc * HORc;
        const float* bfi = b_f   + (size_t)i * HORc;
        const float* bbi = b_b   + (size_t)i * Dd;

        // partial[s] = x @ W_in (split-K), then reduce -> hA
        gemm_mfma<0, 0><<<dim3(Mm / 128, HIDc / 128, SPLITK), 256, 0, stream>>>(
            x, Dd, WtIn + (size_t)i * HIDc * DdPad, DdPad,
            nullptr, nullptr, 0, part, HIDc, Dd, HIDc, KCHUNK);
        reduce_hin<<<Mm * HIDc / 256, 256, 0, stream>>>(part, bi, hA);

        // hidden layers
        gemm_mfma<1, 1><<<dim3(Mm / 128, HIDc / 128, 1), 256, 0, stream>>>(
            hA, HIDc, WtHid + (size_t)(2 * i) * HIDc * HIDc, HIDc,
            bh0, nullptr, 0, hB, HIDc, HIDc, HIDc, HIDc);
        gemm_mfma<1, 1><<<dim3(Mm / 128, HIDc / 128, 1), 256, 0, stream>>>(
            hB, HIDc, WtHid + (size_t)(2 * i + 1) * HIDc * HIDc, HIDc,
            bh1, nullptr, 0, hA, HIDc, HIDc, HIDc, HIDc);

        // forecast accumulate
        gemm_forecast_kernel<<<(Mm * HORc + 255) / 256, 256, 0, stream>>>(
            hA, Wfi, bfi, fc, i > 0 ? 1 : 0);

        // backcast: x = relu(x - (hA @ W_b + b_b)), in place
        gemm_mfma<1, 2><<<dim3(Mm / 128, NbPad / 128, 1), 256, 0, stream>>>(
            hA, HIDc, WtB + (size_t)i * NbPad * HIDc, HIDc,
            bbi, x, Dd, x, Dd, HIDc, Dd, HIDc);
    }

    finalize_kernel<<<(Mm * HORc + 255) / 256, 256, 0, stream>>>(fc, level, fout);
}

// Round 3
// 1098.921 us; speedup vs baseline: 4.0031x; 1.2688x over previous
//
#include <hip/hip_runtime.h>

// Problem constants
#define Bq   8
#define Nn   512
#define Tt   24
#define NIDc 64
#define HIDc 256
#define HORc 24
#define Dd   12376      // Tt + Nn*Tt + NIDc
#define Mm   4096       // Bq*Nn
#define DdPad 12384     // Dd padded to multiple of 32 (K-pad for W_in^T)
#define NbPad 12416     // Dd padded to multiple of 128 (N-pad for W_b^T rows)
#define SPLITK 8
#define KCHUNK 1568     // ceil(12376/(8*32))*32

typedef float  f32x4  __attribute__((ext_vector_type(4)));
typedef short  bf16x8 __attribute__((ext_vector_type(8)));

__device__ __forceinline__ ushort f2bf(float f) {
    unsigned u = __float_as_uint(f);
    u += 0x7FFF + ((u >> 16) & 1);          // RNE; inputs finite
    return (ushort)(u >> 16);
}
__device__ __forceinline__ float bf2f(ushort h) {
    return __uint_as_float(((unsigned)h) << 16);
}

// async 16B/lane global->LDS: LDS dest = wave-uniform base + lane*16
#define ASYNC16(g, l) __builtin_amdgcn_global_load_lds(                        \
    (const __attribute__((address_space(1))) unsigned*)(g),                    \
    (__attribute__((address_space(3))) unsigned*)(l), 16, 0, 0)

// ---------------------------------------------------------------------------
// build level + x0 (fp32, written into backcast region of d_out)
// ---------------------------------------------------------------------------
__global__ __launch_bounds__(256) void build_x_kernel(
    const float* __restrict__ hist, const int* __restrict__ nid,
    const float* __restrict__ adj, const float* __restrict__ emb,
    float* __restrict__ x, float* __restrict__ level)
{
    int bn = blockIdx.x;
    int b  = bn >> 9;
    __shared__ float sh[Tt];
    __shared__ float slv;
    int tid = threadIdx.x;
    const float* hrow = hist + (size_t)bn * Tt;
    if (tid < Tt) sh[tid] = hrow[tid];
    __syncthreads();
    if (tid == 0) {
        float m = sh[0];
        #pragma unroll
        for (int t = 1; t < Tt; t++) m = fmaxf(m, sh[t]);
        slv = m;
        level[bn] = m;
    }
    __syncthreads();
    float lv  = slv;
    float inv = (lv == 0.0f) ? 0.0f : 1.0f / lv;
    float* xr = x + (size_t)bn * Dd;
    if (tid < Tt) xr[tid] = sh[tid] * inv;
    const float* hb   = hist + (size_t)b * Nn * Tt;
    const float* arow = adj  + (size_t)bn * Nn;
    for (int idx = tid; idx < Nn * Tt; idx += 256) {
        int m_ = idx / Tt;
        int t  = idx - m_ * Tt;
        float v = arow[m_] * hb[m_ * Tt + t];
        float r = (v - lv) * inv;
        xr[Tt + idx] = (r > 0.0f) ? r : 0.0f;
    }
    if (tid < NIDc) {
        int id = nid[bn];
        xr[Tt + Nn * Tt + tid] = emb[(size_t)id * NIDc + tid];
    }
}

// ---------------------------------------------------------------------------
// W[K][N] fp32  ->  Bt[n][k] bf16 with K zero-padded to Kpad.
// ---------------------------------------------------------------------------
__global__ __launch_bounds__(256) void transpose_w(
    const float* __restrict__ W, ushort* __restrict__ Bt,
    int K, int N, int Kpad)
{
    __shared__ ushort tile[32][72];
    const int k0 = blockIdx.x * 32;
    const int n0 = blockIdx.y * 64;
    const int tid = threadIdx.x;
    #pragma unroll
    for (int i = 0; i < 8; i++) {
        const int idx = tid + i * 256;
        const int kk = idx >> 6;
        const int nn = idx & 63;
        const int gk = k0 + kk, gn = n0 + nn;
        const float v = (gk < K && gn < N) ? W[(size_t)gk * N + gn] : 0.0f;
        tile[kk][nn] = f2bf(v);
    }
    __syncthreads();
    const int n  = tid >> 2;
    const int kc = (tid & 3) << 3;
    uint4 o;
    o.x = (unsigned)tile[kc + 0][n] | ((unsigned)tile[kc + 1][n] << 16);
    o.y = (unsigned)tile[kc + 2][n] | ((unsigned)tile[kc + 3][n] << 16);
    o.z = (unsigned)tile[kc + 4][n] | ((unsigned)tile[kc + 5][n] << 16);
    o.w = (unsigned)tile[kc + 6][n] | ((unsigned)tile[kc + 7][n] << 16);
    *(uint4*)(Bt + (size_t)(n0 + n) * Kpad + k0 + kc) = o;
}

// ---------------------------------------------------------------------------
// bf16 MFMA GEMM, TMxTN tile, 4 waves (2x2), each wave (TM/32)x(TN/32)
// mfma_f32_16x16x32_bf16. Staging via global_load_lds (16B/lane).
// A row-major [M][lda]: AMODE 0 = fp32 (staged fp32, converted post-ds_read),
//                       AMODE 1 = bf16.
// Bt: bf16 [n][k], pre-padded (rows >= col0+TN, k to mult of 32, zeros).
// EPI 0: raw fp32 partial (split-K slice blockIdx.z)
// EPI 1: bf16 h = relu(acc + bias)
// EPI 2: fp32 C = relu(X - (acc + bias))   (X may alias C; col < N guard)
// ---------------------------------------------------------------------------
template <int TM, int TN, int AMODE, int EPI>
__global__ __launch_bounds__(256) void gemm_mfma(
    const void* __restrict__ Ap, int lda,
    const ushort* __restrict__ Bt, int ldbt,
    const float* __restrict__ bias,
    const float* __restrict__ X, int ldx,
    void* __restrict__ Cp, int ldc,
    int K, int N, int chunk)
{
    constexpr int WI = TM / 32;
    constexpr int WJ = TN / 32;
    __shared__ float  AsF[AMODE == 0 ? TM * 32 : 8];
    __shared__ ushort AsH[AMODE == 1 ? TM * 32 : 8];
    __shared__ ushort Bs[TN * 32];

    const int tid  = threadIdx.x;
    const int row0 = blockIdx.x * TM;
    const int col0 = blockIdx.y * TN;
    const int spl  = blockIdx.z;
    const int kstart = spl * chunk;
    const int kend   = min(K, kstart + chunk);
    const int iters  = (kend - kstart + 31) >> 5;

    const int lane = tid & 63;
    const int wave = tid >> 6;
    const int quad = lane >> 4;
    const int l15  = lane & 15;
    const int wm   = (wave >> 1) * (TM / 2);
    const int wn   = (wave & 1) * (TN / 2);

    f32x4 acc[WI][WJ];
    #pragma unroll
    for (int i = 0; i < WI; i++)
        #pragma unroll
        for (int j = 0; j < WJ; j++)
            acc[i][j] = (f32x4){0.f, 0.f, 0.f, 0.f};

    for (int kt = 0; kt < iters; ++kt) {
        const int kb = kstart + (kt << 5);
        if (AMODE == 0) {
            const float* Ag = (const float*)Ap;
            #pragma unroll
            for (int s = wave; s < TM / 8; s += 4) {     // 8 fp32 rows / segment
                const int r = s * 8 + (lane >> 3);
                ASYNC16(Ag + (size_t)(row0 + r) * lda + kb + ((lane & 7) << 2),
                        AsF + s * 256);
            }
        } else {
            const ushort* Ag = (const ushort*)Ap;
            #pragma unroll
            for (int s = wave; s < TM / 16; s += 4) {    // 16 bf16 rows / segment
                const int r = s * 16 + (lane >> 2);
                ASYNC16(Ag + (size_t)(row0 + r) * lda + kb + ((lane & 3) << 3),
                        AsH + s * 512);
            }
        }
        #pragma unroll
        for (int s = wave; s < TN / 16; s += 4) {
            const int r = s * 16 + (lane >> 2);
            ASYNC16(Bt + (size_t)(col0 + r) * ldbt + kb + ((lane & 3) << 3),
                    Bs + s * 512);
        }
        __syncthreads();   // drains vmcnt before barrier

        if (AMODE == 0 && kb + 32 > kend) {              // ragged K tail: zero pad
            const int kv = kend - kb;                    // valid k in this tile
            const int nz = 32 - kv;
            for (int idx = tid; idx < TM * nz; idx += 256) {
                const int r  = idx / nz;
                const int kk = kv + idx - r * nz;
                AsF[r * 32 + kk] = 0.f;
            }
            __syncthreads();
        }

        bf16x8 af[WI], bfr[WJ];
        #pragma unroll
        for (int i = 0; i < WI; i++) {
            if (AMODE == 0) {
                const float* ar = AsF + (wm + i * 16 + l15) * 32 + quad * 8;
                f32x4 a0 = *(const f32x4*)ar;
                f32x4 a1 = *(const f32x4*)(ar + 4);
                union { bf16x8 v; ushort u[8]; } t;
                t.u[0] = f2bf(a0[0]); t.u[1] = f2bf(a0[1]);
                t.u[2] = f2bf(a0[2]); t.u[3] = f2bf(a0[3]);
                t.u[4] = f2bf(a1[0]); t.u[5] = f2bf(a1[1]);
                t.u[6] = f2bf(a1[2]); t.u[7] = f2bf(a1[3]);
                af[i] = t.v;
            } else {
                af[i] = *(const bf16x8*)&AsH[(wm + i * 16 + l15) * 32 + quad * 8];
            }
        }
        #pragma unroll
        for (int j = 0; j < WJ; j++)
            bfr[j] = *(const bf16x8*)&Bs[(wn + j * 16 + l15) * 32 + quad * 8];
        #pragma unroll
        for (int i = 0; i < WI; i++)
            #pragma unroll
            for (int j = 0; j < WJ; j++)
                acc[i][j] = __builtin_amdgcn_mfma_f32_16x16x32_bf16(
                    af[i], bfr[j], acc[i][j], 0, 0, 0);
        __syncthreads();
    }

    // Epilogue. C/D layout: col = lane&15, row = quad*4 + reg.
    #pragma unroll
    for (int i = 0; i < WI; i++) {
        #pragma unroll
        for (int j = 0; j < WJ; j++) {
            const int rbase = row0 + wm + i * 16 + quad * 4;
            const int c     = col0 + wn + j * 16 + l15;
            #pragma unroll
            for (int r2 = 0; r2 < 4; r2++) {
                const float v = acc[i][j][r2];
                const int row = rbase + r2;
                if (EPI == 0) {
                    ((float*)Cp)[(size_t)spl * Mm * HIDc +
                                 (size_t)row * ldc + c] = v;
                } else if (EPI == 1) {
                    float o = v + bias[c];
                    o = o > 0.f ? o : 0.f;
                    ((ushort*)Cp)[(size_t)row * ldc + c] = f2bf(o);
                } else {
                    if (c < N) {
                        float o = X[(size_t)row * ldx + c] - (v + bias[c]);
                        o = o > 0.f ? o : 0.f;
                        ((float*)Cp)[(size_t)row * ldc + c] = o;
                    }
                }
            }
        }
    }
}

// ---------------------------------------------------------------------------
// h = relu(sum_s partial[s] + bias) -> bf16
// ---------------------------------------------------------------------------
__global__ __launch_bounds__(256) void reduce_hin(
    const float* __restrict__ partial, const float* __restrict__ bias,
    ushort* __restrict__ h)
{
    const int idx = blockIdx.x * 256 + threadIdx.x;
    float s = bias[idx & (HIDc - 1)];
    #pragma unroll
    for (int j = 0; j < SPLITK; j++)
        s += partial[(size_t)j * (Mm * HIDc) + idx];
    s = s > 0.f ? s : 0.f;
    h[idx] = f2bf(s);
}

// ---------------------------------------------------------------------------
// fc[4096x24] (+)= h @ Wf + bf   (h bf16, Wf fp32)
// ---------------------------------------------------------------------------
__global__ __launch_bounds__(256) void gemm_forecast_kernel(
    const ushort* __restrict__ h, const float* __restrict__ Wf,
    const float* __restrict__ bf, float* __restrict__ fc, int accumulate)
{
    int gid = blockIdx.x * 256 + threadIdx.x;
    if (gid >= Mm * HORc) return;
    int row = gid / HORc;
    int col = gid - row * HORc;
    const ushort* hr = h + (size_t)row * HIDc;
    float acc = 0.0f;
    #pragma unroll 4
    for (int k = 0; k < HIDc; k++)
        acc = fmaf(bf2f(hr[k]), Wf[k * HORc + col], acc);
    acc += bf[col];
    if (accumulate) fc[gid] += acc;
    else            fc[gid]  = acc;
}

__global__ __launch_bounds__(256) void finalize_kernel(
    const float* __restrict__ fc, const float* __restrict__ level,
    float* __restrict__ out)
{
    int gid = blockIdx.x * 256 + threadIdx.x;
    if (gid >= Mm * HORc) return;
    out[gid] = fc[gid] * level[gid / HORc];
}

// ---------------------------------------------------------------------------
extern "C" void kernel_launch(void* const* d_in, const int* in_sizes, int n_in,
                              void* d_out, int out_size, void* d_ws, size_t ws_size,
                              hipStream_t stream)
{
    const float* hist  = (const float*)d_in[0];
    const int*   nid   = (const int*)  d_in[1];
    const float* adj   = (const float*)d_in[3];
    const float* emb   = (const float*)d_in[4];
    const float* W_in  = (const float*)d_in[5];
    const float* b_in  = (const float*)d_in[6];
    const float* W_hid = (const float*)d_in[7];
    const float* b_hid = (const float*)d_in[8];
    const float* W_f   = (const float*)d_in[9];
    const float* b_f   = (const float*)d_in[10];
    const float* W_b   = (const float*)d_in[11];
    const float* b_b   = (const float*)d_in[12];

    float* x    = (float*)d_out;                       // backcast region
    float* fout = (float*)d_out + (size_t)Mm * Dd;     // forecast region

    // ws layout (~74 MB)
    char* ws = (char*)d_ws;
    size_t off = 0;
    float*  level = (float*) (ws + off); off += 16384;
    float*  fc    = (float*) (ws + off); off += (size_t)Mm * HORc * 4;
    ushort* hA    = (ushort*)(ws + off); off += (size_t)Mm * HIDc * 2;
    ushort* hB    = (ushort*)(ws + off); off += (size_t)Mm * HIDc * 2;
    ushort* WtIn  = (ushort*)(ws + off); off += (size_t)3 * HIDc * DdPad * 2;
    ushort* WtHid = (ushort*)(ws + off); off += (size_t)6 * HIDc * HIDc * 2;
    ushort* WtB   = (ushort*)(ws + off); off += (size_t)3 * NbPad * HIDc * 2;
    float*  part  = (float*) (ws + off); off += (size_t)SPLITK * Mm * HIDc * 4;

    build_x_kernel<<<Mm, 256, 0, stream>>>(hist, nid, adj, emb, x, level);

    for (int i = 0; i < 3; i++)
        transpose_w<<<dim3(DdPad / 32, HIDc / 64), 256, 0, stream>>>(
            W_in + (size_t)i * Dd * HIDc, WtIn + (size_t)i * HIDc * DdPad,
            Dd, HIDc, DdPad);
    for (int l = 0; l < 6; l++)
        transpose_w<<<dim3(HIDc / 32, HIDc / 64), 256, 0, stream>>>(
            W_hid + (size_t)l * HIDc * HIDc, WtHid + (size_t)l * HIDc * HIDc,
            HIDc, HIDc, HIDc);
    for (int i = 0; i < 3; i++)
        transpose_w<<<dim3(HIDc / 32, NbPad / 64), 256, 0, stream>>>(
            W_b + (size_t)i * HIDc * Dd, WtB + (size_t)i * NbPad * HIDc,
            HIDc, Dd, HIDc);

    for (int i = 0; i < 3; i++) {
        const float* bi  = b_in  + (size_t)i * HIDc;
        const float* bh0 = b_hid + (size_t)(i * 2 + 0) * HIDc;
        const float* bh1 = b_hid + (size_t)(i * 2 + 1) * HIDc;
        const float* Wfi = W_f   + (size_t)i * HIDc * HORc;
        const float* bfi = b_f   + (size_t)i * HORc;
        const float* bbi = b_b   + (size_t)i * Dd;

        // partial[s] = x @ W_in (split-K), then reduce -> hA (bf16)
        gemm_mfma<128, 128, 0, 0>
            <<<dim3(Mm / 128, HIDc / 128, SPLITK), 256, 0, stream>>>(
            x, Dd, WtIn + (size_t)i * HIDc * DdPad, DdPad,
            nullptr, nullptr, 0, part, HIDc, Dd, HIDc, KCHUNK);
        reduce_hin<<<Mm * HIDc / 256, 256, 0, stream>>>(part, bi, hA);

        // hidden layers (64x64 tiles -> 256 blocks)
        gemm_mfma<64, 64, 1, 1>
            <<<dim3(Mm / 64, HIDc / 64, 1), 256, 0, stream>>>(
            hA, HIDc, WtHid + (size_t)(2 * i) * HIDc * HIDc, HIDc,
            bh0, nullptr, 0, hB, HIDc, HIDc, HIDc, HIDc);
        gemm_mfma<64, 64, 1, 1>
            <<<dim3(Mm / 64, HIDc / 64, 1), 256, 0, stream>>>(
            hB, HIDc, WtHid + (size_t)(2 * i + 1) * HIDc * HIDc, HIDc,
            bh1, nullptr, 0, hA, HIDc, HIDc, HIDc, HIDc);

        // forecast accumulate
        gemm_forecast_kernel<<<(Mm * HORc + 255) / 256, 256, 0, stream>>>(
            hA, Wfi, bfi, fc, i > 0 ? 1 : 0);

        // backcast: x = relu(x - (hA @ W_b + b_b)), in place
        gemm_mfma<128, 128, 1, 2>
            <<<dim3(Mm / 128, NbPad / 128, 1), 256, 0, stream>>>(
            hA, HIDc, WtB + (size_t)i * NbPad * HIDc, HIDc,
            bbi, x, Dd, x, Dd, HIDc, Dd, HIDc);
    }

    finalize_kernel<<<(Mm * HORc + 255) / 256, 256, 0, stream>>>(fc, level, fout);
}

// Round 4
// 998.976 us; speedup vs baseline: 4.4036x; 1.1000x over previous
//
#include <hip/hip_runtime.h>

// Problem constants
#define Bq   8
#define Nn   512
#define Tt   24
#define NIDc 64
#define HIDc 256
#define HORc 24
#define Dd   12376      // Tt + Nn*Tt + NIDc
#define Mm   4096       // Bq*Nn
#define DdPad 12384     // Dd padded to multiple of 32 (K dim of x / W_in^T)
#define NbPad 12416     // Dd padded to multiple of 128 (N-pad for W_b^T rows)
#define SPLITK 8
#define KCHUNK 1568     // 8*1568 >= 12384, mult of 32

typedef float  f32x4  __attribute__((ext_vector_type(4)));
typedef short  bf16x8 __attribute__((ext_vector_type(8)));

__device__ __forceinline__ ushort f2bf(float f) {
    unsigned u = __float_as_uint(f);
    u += 0x7FFF + ((u >> 16) & 1);          // RNE; inputs finite
    return (ushort)(u >> 16);
}
__device__ __forceinline__ float bf2f(ushort h) {
    return __uint_as_float(((unsigned)h) << 16);
}

// async 16B/lane global->LDS: LDS dest = wave-uniform base + lane*16
#define ASYNC16(g, l) __builtin_amdgcn_global_load_lds(                        \
    (const __attribute__((address_space(1))) unsigned*)(g),                    \
    (__attribute__((address_space(3))) unsigned*)(l), 16, 0, 0)

// ---------------------------------------------------------------------------
// build level + x0 (bf16, row stride DdPad, pad cols zeroed)
// ---------------------------------------------------------------------------
__global__ __launch_bounds__(256) void build_x_kernel(
    const float* __restrict__ hist, const int* __restrict__ nid,
    const float* __restrict__ adj, const float* __restrict__ emb,
    ushort* __restrict__ x, float* __restrict__ level)
{
    int bn = blockIdx.x;
    int b  = bn >> 9;
    __shared__ float sh[Tt];
    __shared__ float slv;
    int tid = threadIdx.x;
    const float* hrow = hist + (size_t)bn * Tt;
    if (tid < Tt) sh[tid] = hrow[tid];
    __syncthreads();
    if (tid == 0) {
        float m = sh[0];
        #pragma unroll
        for (int t = 1; t < Tt; t++) m = fmaxf(m, sh[t]);
        slv = m;
        level[bn] = m;
    }
    __syncthreads();
    float lv  = slv;
    float inv = (lv == 0.0f) ? 0.0f : 1.0f / lv;
    ushort* xr = x + (size_t)bn * DdPad;
    if (tid < Tt) xr[tid] = f2bf(sh[tid] * inv);
    const float* hb   = hist + (size_t)b * Nn * Tt;
    const float* arow = adj  + (size_t)bn * Nn;
    for (int idx = tid; idx < Nn * Tt; idx += 256) {
        int m_ = idx / Tt;
        int t  = idx - m_ * Tt;
        float v = arow[m_] * hb[m_ * Tt + t];
        float r = (v - lv) * inv;
        xr[Tt + idx] = f2bf((r > 0.0f) ? r : 0.0f);
    }
    if (tid < NIDc) {
        int id = nid[bn];
        xr[Tt + Nn * Tt + tid] = f2bf(emb[(size_t)id * NIDc + tid]);
    }
    if (tid < DdPad - Dd) xr[Dd + tid] = 0;   // zero K-pad cols
}

// ---------------------------------------------------------------------------
// W[K][N] fp32  ->  Bt[n][k] bf16 with K zero-padded to Kpad.
// ---------------------------------------------------------------------------
__global__ __launch_bounds__(256) void transpose_w(
    const float* __restrict__ W, ushort* __restrict__ Bt,
    int K, int N, int Kpad)
{
    __shared__ ushort tile[32][72];
    const int k0 = blockIdx.x * 32;
    const int n0 = blockIdx.y * 64;
    const int tid = threadIdx.x;
    #pragma unroll
    for (int i = 0; i < 8; i++) {
        const int idx = tid + i * 256;
        const int kk = idx >> 6;
        const int nn = idx & 63;
        const int gk = k0 + kk, gn = n0 + nn;
        const float v = (gk < K && gn < N) ? W[(size_t)gk * N + gn] : 0.0f;
        tile[kk][nn] = f2bf(v);
    }
    __syncthreads();
    const int n  = tid >> 2;
    const int kc = (tid & 3) << 3;
    uint4 o;
    o.x = (unsigned)tile[kc + 0][n] | ((unsigned)tile[kc + 1][n] << 16);
    o.y = (unsigned)tile[kc + 2][n] | ((unsigned)tile[kc + 3][n] << 16);
    o.z = (unsigned)tile[kc + 4][n] | ((unsigned)tile[kc + 5][n] << 16);
    o.w = (unsigned)tile[kc + 6][n] | ((unsigned)tile[kc + 7][n] << 16);
    *(uint4*)(Bt + (size_t)(n0 + n) * Kpad + k0 + kc) = o;
}

// ---------------------------------------------------------------------------
// bf16 MFMA GEMM, TMxTN tile, 4 waves (2x2), mfma_f32_16x16x32_bf16.
// A: bf16 row-major [M][lda]; Bt: bf16 [n][k] pre-padded. Staging via
// global_load_lds 16B/lane.
// EPI 0: fp32 split-K partial (slice = blockIdx.z)
// EPI 1: bf16 h = relu(acc + bias)
// EPI 2: fp32 C = relu(X - (acc + bias)), X bf16 (final backcast)
// EPI 3: bf16 C = relu(X - (acc + bias)), in-place (X == C)
// ---------------------------------------------------------------------------
template <int TM, int TN, int EPI>
__global__ __launch_bounds__(256) void gemm_mfma(
    const ushort* __restrict__ A, int lda,
    const ushort* __restrict__ Bt, int ldbt,
    const float* __restrict__ bias,
    const ushort* __restrict__ X, int ldx,
    void* __restrict__ Cp, int ldc,
    int K, int N, int chunk)
{
    constexpr int WI = TM / 32;
    constexpr int WJ = TN / 32;
    __shared__ ushort As[TM * 32];
    __shared__ ushort Bs[TN * 32];

    const int tid  = threadIdx.x;
    const int row0 = blockIdx.x * TM;
    const int col0 = blockIdx.y * TN;
    const int spl  = blockIdx.z;
    const int kstart = spl * chunk;
    const int kend   = min(K, kstart + chunk);
    const int iters  = (kend - kstart) >> 5;   // K, chunk multiples of 32

    const int lane = tid & 63;
    const int wave = tid >> 6;
    const int quad = lane >> 4;
    const int l15  = lane & 15;
    const int wm   = (wave >> 1) * (TM / 2);
    const int wn   = (wave & 1) * (TN / 2);

    f32x4 acc[WI][WJ];
    #pragma unroll
    for (int i = 0; i < WI; i++)
        #pragma unroll
        for (int j = 0; j < WJ; j++)
            acc[i][j] = (f32x4){0.f, 0.f, 0.f, 0.f};

    for (int kt = 0; kt < iters; ++kt) {
        const int kb = kstart + (kt << 5);
        #pragma unroll
        for (int s = wave; s < TM / 16; s += 4) {    // 16 bf16 rows / segment
            const int r = s * 16 + (lane >> 2);
            ASYNC16(A + (size_t)(row0 + r) * lda + kb + ((lane & 3) << 3),
                    As + s * 512);
        }
        #pragma unroll
        for (int s = wave; s < TN / 16; s += 4) {
            const int r = s * 16 + (lane >> 2);
            ASYNC16(Bt + (size_t)(col0 + r) * ldbt + kb + ((lane & 3) << 3),
                    Bs + s * 512);
        }
        __syncthreads();

        bf16x8 af[WI], bfr[WJ];
        #pragma unroll
        for (int i = 0; i < WI; i++)
            af[i] = *(const bf16x8*)&As[(wm + i * 16 + l15) * 32 + quad * 8];
        #pragma unroll
        for (int j = 0; j < WJ; j++)
            bfr[j] = *(const bf16x8*)&Bs[(wn + j * 16 + l15) * 32 + quad * 8];
        #pragma unroll
        for (int i = 0; i < WI; i++)
            #pragma unroll
            for (int j = 0; j < WJ; j++)
                acc[i][j] = __builtin_amdgcn_mfma_f32_16x16x32_bf16(
                    af[i], bfr[j], acc[i][j], 0, 0, 0);
        __syncthreads();
    }

    // Epilogue. C/D layout: col = lane&15, row = quad*4 + reg.
    #pragma unroll
    for (int i = 0; i < WI; i++) {
        const int rbase = row0 + wm + i * 16 + quad * 4;
        float xv[WJ][4];
        if (EPI >= 2) {      // preload X for this row-group (MLP)
            #pragma unroll
            for (int j = 0; j < WJ; j++) {
                const int c = col0 + wn + j * 16 + l15;
                #pragma unroll
                for (int r2 = 0; r2 < 4; r2++)
                    xv[j][r2] = (c < N)
                        ? bf2f(X[(size_t)(rbase + r2) * ldx + c]) : 0.f;
            }
        }
        #pragma unroll
        for (int j = 0; j < WJ; j++) {
            const int c = col0 + wn + j * 16 + l15;
            #pragma unroll
            for (int r2 = 0; r2 < 4; r2++) {
                const float v = acc[i][j][r2];
                const int row = rbase + r2;
                if (EPI == 0) {
                    ((float*)Cp)[(size_t)spl * Mm * HIDc +
                                 (size_t)row * ldc + c] = v;
                } else if (EPI == 1) {
                    float o = v + bias[c];
                    o = o > 0.f ? o : 0.f;
                    ((ushort*)Cp)[(size_t)row * ldc + c] = f2bf(o);
                } else if (EPI == 2) {
                    if (c < N) {
                        float o = xv[j][r2] - (v + bias[c]);
                        o = o > 0.f ? o : 0.f;
                        ((float*)Cp)[(size_t)row * ldc + c] = o;
                    }
                } else {
                    if (c < N) {
                        float o = xv[j][r2] - (v + bias[c]);
                        o = o > 0.f ? o : 0.f;
                        ((ushort*)Cp)[(size_t)row * ldc + c] = f2bf(o);
                    }
                }
            }
        }
    }
}

// ---------------------------------------------------------------------------
// h = relu(sum_s partial[s] + bias) -> bf16
// ---------------------------------------------------------------------------
__global__ __launch_bounds__(256) void reduce_hin(
    const float* __restrict__ partial, const float* __restrict__ bias,
    ushort* __restrict__ h)
{
    const int idx = blockIdx.x * 256 + threadIdx.x;
    float s = bias[idx & (HIDc - 1)];
    #pragma unroll
    for (int j = 0; j < SPLITK; j++)
        s += partial[(size_t)j * (Mm * HIDc) + idx];
    s = s > 0.f ? s : 0.f;
    h[idx] = f2bf(s);
}

// ---------------------------------------------------------------------------
// fc[4096x24] (+)= h @ Wf + bf   (h bf16, Wf fp32)
// ---------------------------------------------------------------------------
__global__ __launch_bounds__(256) void gemm_forecast_kernel(
    const ushort* __restrict__ h, const float* __restrict__ Wf,
    const float* __restrict__ bf, float* __restrict__ fc, int accumulate)
{
    int gid = blockIdx.x * 256 + threadIdx.x;
    if (gid >= Mm * HORc) return;
    int row = gid / HORc;
    int col = gid - row * HORc;
    const ushort* hr = h + (size_t)row * HIDc;
    float acc = 0.0f;
    #pragma unroll 4
    for (int k = 0; k < HIDc; k++)
        acc = fmaf(bf2f(hr[k]), Wf[k * HORc + col], acc);
    acc += bf[col];
    if (accumulate) fc[gid] += acc;
    else            fc[gid]  = acc;
}

__global__ __launch_bounds__(256) void finalize_kernel(
    const float* __restrict__ fc, const float* __restrict__ level,
    float* __restrict__ out)
{
    int gid = blockIdx.x * 256 + threadIdx.x;
    if (gid >= Mm * HORc) return;
    out[gid] = fc[gid] * level[gid / HORc];
}

// ---------------------------------------------------------------------------
extern "C" void kernel_launch(void* const* d_in, const int* in_sizes, int n_in,
                              void* d_out, int out_size, void* d_ws, size_t ws_size,
                              hipStream_t stream)
{
    const float* hist  = (const float*)d_in[0];
    const int*   nid   = (const int*)  d_in[1];
    const float* adj   = (const float*)d_in[3];
    const float* emb   = (const float*)d_in[4];
    const float* W_in  = (const float*)d_in[5];
    const float* b_in  = (const float*)d_in[6];
    const float* W_hid = (const float*)d_in[7];
    const float* b_hid = (const float*)d_in[8];
    const float* W_f   = (const float*)d_in[9];
    const float* b_f   = (const float*)d_in[10];
    const float* W_b   = (const float*)d_in[11];
    const float* b_b   = (const float*)d_in[12];

    float* bout = (float*)d_out;                       // backcast (B,N,D) fp32
    float* fout = (float*)d_out + (size_t)Mm * Dd;     // forecast region

    // ws layout (~178 MB)
    char* ws = (char*)d_ws;
    size_t off = 0;
    float*  level = (float*) (ws + off); off += 16384;
    float*  fc    = (float*) (ws + off); off += (size_t)Mm * HORc * 4;
    ushort* hA    = (ushort*)(ws + off); off += (size_t)Mm * HIDc * 2;
    ushort* hB    = (ushort*)(ws + off); off += (size_t)Mm * HIDc * 2;
    ushort* WtIn  = (ushort*)(ws + off); off += (size_t)3 * HIDc * DdPad * 2;
    ushort* WtHid = (ushort*)(ws + off); off += (size_t)6 * HIDc * HIDc * 2;
    ushort* WtB   = (ushort*)(ws + off); off += (size_t)3 * NbPad * HIDc * 2;
    float*  part  = (float*) (ws + off); off += (size_t)SPLITK * Mm * HIDc * 4;
    ushort* xb    = (ushort*)(ws + off); off += (size_t)Mm * DdPad * 2;

    build_x_kernel<<<Mm, 256, 0, stream>>>(hist, nid, adj, emb, xb, level);

    for (int i = 0; i < 3; i++)
        transpose_w<<<dim3(DdPad / 32, HIDc / 64), 256, 0, stream>>>(
            W_in + (size_t)i * Dd * HIDc, WtIn + (size_t)i * HIDc * DdPad,
            Dd, HIDc, DdPad);
    for (int l = 0; l < 6; l++)
        transpose_w<<<dim3(HIDc / 32, HIDc / 64), 256, 0, stream>>>(
            W_hid + (size_t)l * HIDc * HIDc, WtHid + (size_t)l * HIDc * HIDc,
            HIDc, HIDc, HIDc);
    for (int i = 0; i < 3; i++)
        transpose_w<<<dim3(HIDc / 32, NbPad / 64), 256, 0, stream>>>(
            W_b + (size_t)i * HIDc * Dd, WtB + (size_t)i * NbPad * HIDc,
            HIDc, Dd, HIDc);

    for (int i = 0; i < 3; i++) {
        const float* bi  = b_in  + (size_t)i * HIDc;
        const float* bh0 = b_hid + (size_t)(i * 2 + 0) * HIDc;
        const float* bh1 = b_hid + (size_t)(i * 2 + 1) * HIDc;
        const float* Wfi = W_f   + (size_t)i * HIDc * HORc;
        const float* bfi = b_f   + (size_t)i * HORc;
        const float* bbi = b_b   + (size_t)i * Dd;

        // partial[s] = x @ W_in (split-K over K=DdPad), reduce -> hA (bf16)
        gemm_mfma<128, 128, 0>
            <<<dim3(Mm / 128, HIDc / 128, SPLITK), 256, 0, stream>>>(
            xb, DdPad, WtIn + (size_t)i * HIDc * DdPad, DdPad,
            nullptr, nullptr, 0, part, HIDc, DdPad, HIDc, KCHUNK);
        reduce_hin<<<Mm * HIDc / 256, 256, 0, stream>>>(part, bi, hA);

        // hidden layers (64x64 tiles -> 256 blocks)
        gemm_mfma<64, 64, 1>
            <<<dim3(Mm / 64, HIDc / 64, 1), 256, 0, stream>>>(
            hA, HIDc, WtHid + (size_t)(2 * i) * HIDc * HIDc, HIDc,
            bh0, nullptr, 0, hB, HIDc, HIDc, HIDc, HIDc);
        gemm_mfma<64, 64, 1>
            <<<dim3(Mm / 64, HIDc / 64, 1), 256, 0, stream>>>(
            hB, HIDc, WtHid + (size_t)(2 * i + 1) * HIDc * HIDc, HIDc,
            bh1, nullptr, 0, hA, HIDc, HIDc, HIDc, HIDc);

        // forecast accumulate
        gemm_forecast_kernel<<<(Mm * HORc + 255) / 256, 256, 0, stream>>>(
            hA, Wfi, bfi, fc, i > 0 ? 1 : 0);

        // backcast
        if (i < 2) {
            // xb = relu(xb - (hA @ W_b + b_b)), in-place bf16
            gemm_mfma<128, 128, 3>
                <<<dim3(Mm / 128, NbPad / 128, 1), 256, 0, stream>>>(
                hA, HIDc, WtB + (size_t)i * NbPad * HIDc, HIDc,
                bbi, xb, DdPad, xb, DdPad, HIDc, Dd, HIDc);
        } else {
            // final: bout = relu(xb - (hA @ W_b + b_b)), fp32 output
            gemm_mfma<128, 128, 2>
                <<<dim3(Mm / 128, NbPad / 128, 1), 256, 0, stream>>>(
                hA, HIDc, WtB + (size_t)i * NbPad * HIDc, HIDc,
                bbi, xb, DdPad, bout, Dd, HIDc, Dd, HIDc);
        }
    }

    finalize_kernel<<<(Mm * HORc + 255) / 256, 256, 0, stream>>>(fc, level, fout);
}